// Round 12
// baseline (391.906 us; speedup 1.0000x reference)
//
#include <hip/hip_runtime.h>
#include <hip/hip_bf16.h>

#define B_   8
#define T_   1024
#define HID_ 1024
#define NH_  16
#define HD_  64
#define K2   2048   // 2-term split K for the Wo GEMM: [hi|lo] x [hi|hi]

typedef __attribute__((ext_vector_type(8))) short bf16x8;
typedef __attribute__((ext_vector_type(4))) float f32x4;

__device__ __forceinline__ void gl_lds16(const void* g, void* l) {
    __builtin_amdgcn_global_load_lds((const __attribute__((address_space(1))) void*)g,
                                     (__attribute__((address_space(3))) void*)l, 16, 0, 0);
}

__device__ __forceinline__ float fast_exp2(float x) {
    return __builtin_amdgcn_exp2f(x);   // v_exp_f32
}

// ---------------------------------------------------------------------------
// Fused prep: one launch covers
//   [0,8192)      : cast x (fp32->bf16, 4/thread)
//   [8192,9216)   : cast Wq
//   [9216,10240)  : cast Wk
//   [10240,11264) : cast Wv
//   [11264,12288) : dup-cast Wo into [hi|hi] K2 layout
//   [12288,45056) : mask_pack (ballot bit-pack) + inline tdense clear
// tdense is memset to ~0 (dense) before this launch; any wave whose 64-bit
// ballot isn't all-ones clears its (b,qt,kt) tile with a device-scope
// atomicAnd. All-ones masks execute ZERO atomics.
// ---------------------------------------------------------------------------
__global__ __launch_bounds__(256) void prep_fused(const float* __restrict__ x,
                                                  const float* __restrict__ Wq,
                                                  const float* __restrict__ Wk,
                                                  const float* __restrict__ Wv,
                                                  const float* __restrict__ Wo,
                                                  const int* __restrict__ mask,
                                                  __hip_bfloat16* __restrict__ xb,
                                                  __hip_bfloat16* __restrict__ wqkv,
                                                  __hip_bfloat16* __restrict__ wo,
                                                  unsigned long long* __restrict__ mbits,
                                                  unsigned int* __restrict__ tdense) {
    const int bid = blockIdx.x;
    const int tid = threadIdx.x;
    if (bid < 12288) {
        const float* X;
        __hip_bfloat16* Y;
        int lb;
        if (bid < 8192)       { X = x;  Y = xb;                              lb = bid; }
        else if (bid < 9216)  { X = Wq; Y = wqkv;                            lb = bid - 8192; }
        else if (bid < 10240) { X = Wk; Y = wqkv + (size_t)1024 * 1024;      lb = bid - 9216; }
        else if (bid < 11264) { X = Wv; Y = wqkv + (size_t)2048 * 1024;      lb = bid - 10240; }
        else                  { X = Wo; Y = wo;                              lb = bid - 11264; }
        int gid = lb * 256 + tid;
        int f = gid << 2;
        float4 xv = *(const float4*)(X + f);
        union { __hip_bfloat16 b[4]; ushort4 u; } p;
        p.b[0] = __float2bfloat16(xv.x);
        p.b[1] = __float2bfloat16(xv.y);
        p.b[2] = __float2bfloat16(xv.z);
        p.b[3] = __float2bfloat16(xv.w);
        if (bid < 11264) {
            *(ushort4*)(Y + f) = p.u;
        } else {
            int m = f >> 10, kk = f & 1023;
            size_t base = (size_t)m * K2 + kk;
            *(ushort4*)(Y + base) = p.u;
            *(ushort4*)(Y + base + 1024) = p.u;
        }
    } else {
        int gid = (bid - 12288) * 256 + tid;
        int wid = gid >> 6;                    // (b*T + t)*16 + kt
        int lane = tid & 63;
        int m = mask[(size_t)wid * 64 + lane];
        unsigned long long bal = __ballot(m != 0);
        if (lane == 0) {
            mbits[wid] = bal;
            if (bal != ~0ull) {
                int b  = wid >> 14;
                int t  = (wid >> 4) & 1023;
                int kt = wid & 15;
                atomicAnd(&tdense[(b * 16 + (t >> 6)) * 16 + kt], 0u);
            }
        }
    }
}

// ---------------------------------------------------------------------------
// bf16 MFMA GEMM, v7-verified K-loop (best measured config): 128x128 tile,
// BK=64 staged as TWO 128x32 column-blocks; stage -> barrier -> compute both
// -> barrier. 32KB LDS, 4 blocks/CU.
// Dead levers (measured, do not retry): (256,5) [v6: 64V+64A=128 regs caps 4
// waves/SIMD; 5 forces spill]; XCD swizzle [v8: FETCH 79->85MB]; BK=32
// explicit dbuf [v9: 75->84us, halves MLP/ILP; TLP already hides latency];
// BN=64 Wo tile [v10: Wo 60->72us, arithmetic intensity loss beats TLP gain].
// KD = K depth. MODE 0: fp32 C (Wo GEMM). MODE 2: fused QKV epilogue.
// ---------------------------------------------------------------------------
template<int MODE, int KD>
__global__ __launch_bounds__(256, 4) void gemm_mfma(const __hip_bfloat16* __restrict__ A,
                                                    const __hip_bfloat16* __restrict__ Wp,
                                                    float* __restrict__ C0,
                                                    __hip_bfloat16* __restrict__ qbf,
                                                    __hip_bfloat16* __restrict__ kbf,
                                                    __hip_bfloat16* __restrict__ vt,
                                                    const float* __restrict__ cost,
                                                    const float* __restrict__ sint,
                                                    const int* __restrict__ ts) {
    __shared__ __hip_bfloat16 As[2][128 * 32];
    __shared__ __hip_bfloat16 Bs[2][128 * 32];
    const int tid = threadIdx.x;
    const int lane = tid & 63;
    const int w = tid >> 6;
    const int wm = w >> 1, wn = w & 1;
    const int m0 = blockIdx.y * 128, n0 = blockIdx.x * 128;
    const int r0 = tid >> 2;            // 0..63
    const int ks = (tid & 3) << 3;      // 0,8,16,24
    const int ml = lane & 15;
    const int kg = (lane >> 4) << 3;
    const int q4 = (lane >> 4) << 2;

    f32x4 acc[4][4];
#pragma unroll
    for (int i = 0; i < 4; ++i)
#pragma unroll
        for (int j = 0; j < 4; ++j) acc[i][j] = (f32x4){0.f, 0.f, 0.f, 0.f};

    for (int k0 = 0; k0 < KD; k0 += 64) {
#pragma unroll
        for (int c = 0; c < 2; ++c) {
            const int kc = k0 + c * 32 + ks;
            gl_lds16(A  + (size_t)(m0 + r0)      * KD + kc, &As[c][r0 * 32 + ks]);
            gl_lds16(A  + (size_t)(m0 + 64 + r0) * KD + kc, &As[c][(64 + r0) * 32 + ks]);
            gl_lds16(Wp + (size_t)(n0 + r0)      * KD + kc, &Bs[c][r0 * 32 + ks]);
            gl_lds16(Wp + (size_t)(n0 + 64 + r0) * KD + kc, &Bs[c][(64 + r0) * 32 + ks]);
        }
        __syncthreads();

#pragma unroll
        for (int c = 0; c < 2; ++c) {
            bf16x8 a[4], b[4];
#pragma unroll
            for (int mi = 0; mi < 4; ++mi)
                a[mi] = *(const bf16x8*)(&As[c][(wm * 64 + mi * 16 + ml) * 32 + kg]);
#pragma unroll
            for (int ni = 0; ni < 4; ++ni)
                b[ni] = *(const bf16x8*)(&Bs[c][(wn * 64 + ni * 16 + ml) * 32 + kg]);
#pragma unroll
            for (int mi = 0; mi < 4; ++mi)
#pragma unroll
                for (int ni = 0; ni < 4; ++ni)
                    acc[mi][ni] = __builtin_amdgcn_mfma_f32_16x16x32_bf16(a[mi], b[ni], acc[mi][ni], 0, 0, 0);
        }
        __syncthreads();
    }

    if (MODE == 0) {
#pragma unroll
        for (int mi = 0; mi < 4; ++mi)
#pragma unroll
            for (int ni = 0; ni < 4; ++ni) {
                int n = n0 + wn * 64 + ni * 16 + ml;
#pragma unroll
                for (int r = 0; r < 4; ++r) {
                    int m = m0 + wm * 64 + mi * 16 + q4 + r;
                    C0[(size_t)m * 1024 + n] = acc[mi][ni][r];
                }
            }
    } else {
        const int nB = n0 + wn * 64;        // wave-uniform, 64-aligned
        const int sel = nB >> 10;           // 0=Q 1=K 2=V
        const int h = (nB & 1023) >> 6;
        if (sel < 2) {
            __hip_bfloat16* dst = sel ? kbf : qbf;
#pragma unroll
            for (int mi = 0; mi < 4; ++mi) {
#pragma unroll
                for (int r = 0; r < 4; ++r) {
                    int m = m0 + wm * 64 + mi * 16 + q4 + r;
                    int tsv = ts[m];
                    int bb = m >> 10, t = m & 1023;
                    size_t rowoff = ((size_t)(bb * NH_ + h) * T_ + t) * HD_;
#pragma unroll
                    for (int ni = 0; ni < 4; ++ni) {
                        int d = ni * 16 + ml;
                        float c = cost[tsv * HD_ + d];
                        float s = sint[tsv * HD_ + d];
                        float u  = acc[mi][ni][r];
                        float up = acc[mi][ni ^ 2][r];
                        float o = (ni < 2) ? (u * c - up * s) : (u * c + up * s);
                        dst[rowoff + d] = __float2bfloat16(o);
                    }
                }
            }
        } else {
#pragma unroll
            for (int mi = 0; mi < 4; ++mi)
#pragma unroll
                for (int r = 0; r < 4; ++r) {
                    int m = m0 + wm * 64 + mi * 16 + q4 + r;
                    int bb = m >> 10, t = m & 1023;
#pragma unroll
                    for (int ni = 0; ni < 4; ++ni) {
                        int d = ni * 16 + ml;
                        vt[((size_t)(bb * NH_ + h) * HD_ + d) * T_ + t] =
                            __float2bfloat16(acc[mi][ni][r]);
                    }
                }
        }
    }
}

// ---------------------------------------------------------------------------
// MFMA flash attention v12. Swapped QK^T, swizzled gl_lds16 K staging,
// packed Ps round-trip, wave-uniform dense/masked branch, 2048-block grid.
// NEW: V is NOT LDS-staged (guide m169: at S=1024 K/V is L2-resident and
// V-staging is pure overhead). vt is already globally transposed (b,h,d,t),
// so the PV B-fragment is a plain 16B global load per lane (4 lanes x 64B
// contiguous per row; L1 absorbs the 4-wave redundancy; 12 heads/XCD x
// 256KB = 3MB < 4MB L2 at 6 blocks/CU -- under the v6 thrash threshold).
// LDS 40960 -> 24576 B => 6 blocks/CU (was 4): +50% TLP on the
// latency-bound kernel.
// ---------------------------------------------------------------------------
__global__ __launch_bounds__(256, 6) void flash_mfma(const __hip_bfloat16* __restrict__ qg,
                                                     const __hip_bfloat16* __restrict__ kg_,
                                                     const __hip_bfloat16* __restrict__ vtg,
                                                     const unsigned long long* __restrict__ mbits,
                                                     const unsigned int* __restrict__ tdense,
                                                     __hip_bfloat16* __restrict__ xs) {
    __shared__ __hip_bfloat16 Ks[2][64 * 64];   // 16 KB, granule-swizzled
    __shared__ __hip_bfloat16 Ps[4][16 * 64];   // 8 KB, per-wave P: [q][kv], swizzled
    const int id = blockIdx.x;
    const int qt = (id >> 3) & 15;
    const int hb = ((id >> 7) << 3) | (id & 7);
    const int h = hb & 15, b = hb >> 4;
    const int tid = threadIdx.x;
    const int lane = tid & 63;
    const int w = tid >> 6;
    const int ml = lane & 15;
    const int g4 = lane >> 4;                 // 0..3
    const int kg8 = g4 << 3;
    const int q4 = g4 << 2;
    const int q0 = qt * 64;
    const size_t bh_off = (size_t)(b * NH_ + h) * T_ * HD_;
    const __hip_bfloat16* qb = qg + bh_off;
    const __hip_bfloat16* kb = kg_ + bh_off;
    const __hip_bfloat16* vtb = vtg + bh_off;   // (d, t) rows, read direct
    const float SCL = 0.125f * 1.44269504f;     // scale * log2(e), for exp2

    // K staging geometry: lane covers (row = rbase + lane>>3, dest granule
    // lane&7); source granule pre-swizzled so LDS slot g' holds global
    // g' ^ (row&7).
    const int srow = lane >> 3;               // 0..7
    const int sg8 = ((lane & 7) ^ srow) << 3; // swizzled source col (bf16 elems)
    // fragment-read swizzle: byte offset of granule g4 at row r is
    //   16 * (g4 ^ (r & 7));  second half (cols +32) is that ^ 64.
    const int sx = ((g4 ^ (ml & 7)) << 4);
    const int pswz = (ml & 7) << 4;           // P-store granule swizzle key

    bf16x8 qf0 = *(const bf16x8*)(qb + (size_t)(q0 + w * 16 + ml) * HD_ + kg8);
    bf16x8 qf1 = *(const bf16x8*)(qb + (size_t)(q0 + w * 16 + ml) * HD_ + 32 + kg8);

    f32x4 acc_o[4];
    float lsum = 0.f;
#pragma unroll
    for (int i = 0; i < 4; ++i) acc_o[i] = (f32x4){0.f, 0.f, 0.f, 0.f};
    char* psw = (char*)&Ps[w][0];

    // prologue: stage K-tile 0 into buffer 0 (async; first barrier drains)
#pragma unroll
    for (int p = 0; p < 2; ++p) {
        const int rbase = p * 32 + w * 8;
        gl_lds16(kb + (size_t)(rbase + srow) * HD_ + sg8, &Ks[0][rbase * 64]);
    }

    for (int kt = 0; kt < 16; ++kt) {
        const int cur = kt & 1;
        __syncthreads();   // vmcnt(0): staged K-tile 'cur' complete; buffer cur^1 free
        if (kt < 15) {
            const int k0n = (kt + 1) * 64;
            const int nb = cur ^ 1;
#pragma unroll
            for (int p = 0; p < 2; ++p) {
                const int rbase = p * 32 + w * 8;
                gl_lds16(kb + (size_t)(k0n + rbase + srow) * HD_ + sg8, &Ks[nb][rbase * 64]);
            }
        }

        // S^T = K @ Q^T : sacc[ni][r] = S[q = w*16+ml][kv = ni*16 + q4 + r]
        f32x4 sacc[4];
#pragma unroll
        for (int ni = 0; ni < 4; ++ni) sacc[ni] = (f32x4){0.f, 0.f, 0.f, 0.f};
        const char* ksb = (const char*)&Ks[cur][0];
#pragma unroll
        for (int ni = 0; ni < 4; ++ni) {
            const char* rp = ksb + (ni * 16 + ml) * 128;
            bf16x8 kf0 = *(const bf16x8*)(rp + sx);
            bf16x8 kf1 = *(const bf16x8*)(rp + (sx ^ 64));
            sacc[ni] = __builtin_amdgcn_mfma_f32_16x16x32_bf16(kf0, qf0, sacc[ni], 0, 0, 0);
            sacc[ni] = __builtin_amdgcn_mfma_f32_16x16x32_bf16(kf1, qf1, sacc[ni], 0, 0, 0);
        }

        // softmax numerator (no max subtraction; scores bounded).
        // Dense/masked split is wave-uniform (tdense depends on b,qt,kt only).
        if (tdense[(b * 16 + qt) * 16 + kt]) {
#pragma unroll
            for (int ni = 0; ni < 4; ++ni) {
                float pv[4];
#pragma unroll
                for (int r = 0; r < 4; ++r) pv[r] = fast_exp2(sacc[ni][r] * SCL);
                lsum += (pv[0] + pv[1]) + (pv[2] + pv[3]);
                union { __hip_bfloat16 bb[4]; unsigned long long u8; } pk;
                pk.bb[0] = __float2bfloat16(pv[0]);
                pk.bb[1] = __float2bfloat16(pv[1]);
                pk.bb[2] = __float2bfloat16(pv[2]);
                pk.bb[3] = __float2bfloat16(pv[3]);
                *(unsigned long long*)(psw + ml * 128 + ((ni * 32 + g4 * 8) ^ pswz)) = pk.u8;
            }
        } else {
            // One mask word per lane (its q-row = w*16+ml); bit index = kv.
            unsigned long long mb =
                mbits[((size_t)(b * T_ + q0 + w * 16 + ml)) * 16 + kt];
#pragma unroll
            for (int ni = 0; ni < 4; ++ni) {
                float pv[4];
#pragma unroll
                for (int r = 0; r < 4; ++r) {
                    int kv = ni * 16 + q4 + r;
                    pv[r] = ((mb >> kv) & 1ull) ? fast_exp2(sacc[ni][r] * SCL) : 0.f;
                }
                lsum += (pv[0] + pv[1]) + (pv[2] + pv[3]);
                union { __hip_bfloat16 bb[4]; unsigned long long u8; } pk;
                pk.bb[0] = __float2bfloat16(pv[0]);
                pk.bb[1] = __float2bfloat16(pv[1]);
                pk.bb[2] = __float2bfloat16(pv[2]);
                pk.bb[3] = __float2bfloat16(pv[3]);
                *(unsigned long long*)(psw + ml * 128 + ((ni * 32 + g4 * 8) ^ pswz)) = pk.u8;
            }
        }

        // P fragments: lane needs P[q=ml][kv = 8g4+e] and [32+8g4+e] -> two
        // 16B-contiguous swizzled reads (same sx un-swizzle as K rows).
        bf16x8 pf0 = *(const bf16x8*)(psw + ml * 128 + sx);
        bf16x8 pf1 = *(const bf16x8*)(psw + ml * 128 + (sx ^ 64));

        // O += P @ V : V read DIRECT from global vt (b,h,d,t); lane (g4,ml)
        // reads row d = dt*16+ml, cols kt*64 + 8*g4 (+32). 4 lanes x 64B
        // contiguous per row; L2-resident.
#pragma unroll
        for (int dt = 0; dt < 4; ++dt) {
            const __hip_bfloat16* vrow = vtb + (size_t)(dt * 16 + ml) * T_ + kt * 64 + kg8;
            bf16x8 vf0 = *(const bf16x8*)(vrow);
            bf16x8 vf1 = *(const bf16x8*)(vrow + 32);
            acc_o[dt] = __builtin_amdgcn_mfma_f32_16x16x32_bf16(pf0, vf0, acc_o[dt], 0, 0, 0);
            acc_o[dt] = __builtin_amdgcn_mfma_f32_16x16x32_bf16(pf1, vf1, acc_o[dt], 0, 0, 0);
        }
    }

    // epilogue: lane's lsum covers kv in {16ni+q4+r} for q = w*16+ml.
    // Reduce across the 4 lane-groups sharing ml -> total l per q-row.
    float l = lsum;
    l += __shfl_xor(l, 16);
    l += __shfl_xor(l, 32);
    // acc_o rows are q = q4+r: pull l for that row from lane (16*g4 + q4+r).
#pragma unroll
    for (int r = 0; r < 4; ++r) {
        float lr = __shfl(l, q4 + r, 16);
        float inv = 1.0f / lr;
        size_t rb = (size_t)(b * T_ + q0 + w * 16 + q4 + r) * K2;
#pragma unroll
        for (int dt = 0; dt < 4; ++dt) {
            float val = acc_o[dt][r] * inv;
            int col = h * HD_ + dt * 16 + ml;
            __hip_bfloat16 hi = __float2bfloat16(val);
            __hip_bfloat16 lo = __float2bfloat16(val - __bfloat162float(hi));
            xs[rb + col] = hi;
            xs[rb + 1024 + col] = lo;
        }
    }
}

// ---------------------------------------------------------------------------
extern "C" void kernel_launch(void* const* d_in, const int* in_sizes, int n_in,
                              void* d_out, int out_size, void* d_ws, size_t ws_size,
                              hipStream_t stream) {
    const float* x    = (const float*)d_in[0];
    const float* Wq   = (const float*)d_in[1];
    const float* Wk   = (const float*)d_in[2];
    const float* Wv   = (const float*)d_in[3];
    const float* Wo   = (const float*)d_in[4];
    const float* cost = (const float*)d_in[5];
    const float* sint = (const float*)d_in[6];
    const int*   mask = (const int*)d_in[7];
    const int*   ts   = (const int*)d_in[8];
    float* out = (float*)d_out;

    const size_t MB = 1ull << 20;
    char* wsp = (char*)d_ws;
    __hip_bfloat16* qbf  = (__hip_bfloat16*)(wsp + 0 * MB);     // 16 MB
    __hip_bfloat16* kbf  = (__hip_bfloat16*)(wsp + 16 * MB);    // 16 MB
    __hip_bfloat16* vt   = (__hip_bfloat16*)(wsp + 32 * MB);    // 16 MB (b,h,d,t)
    __hip_bfloat16* xs   = (__hip_bfloat16*)(wsp + 48 * MB);    // 32 MB (ctx 2-term split)
    __hip_bfloat16* xb   = (__hip_bfloat16*)(wsp + 80 * MB);    // 16 MB (x cast)
    __hip_bfloat16* wqkv = (__hip_bfloat16*)(wsp + 96 * MB);    // 6 MB (3072 x 1024)
    __hip_bfloat16* wo   = (__hip_bfloat16*)(wsp + 102 * MB);   // 4 MB (1024 x K2)
    unsigned long long* mbits = (unsigned long long*)(wsp + 106 * MB);  // 1 MB
    unsigned int* tdense = (unsigned int*)(wsp + 107 * MB);             // 16 KB

    // tdense init: all tiles dense (0xFFFFFFFF); mask_pack waves clear
    // non-dense tiles via predicated atomicAnd (zero atomics on all-ones mask).
    hipMemsetAsync(tdense, 0xFF, 4096 * sizeof(unsigned int), stream);

    // fused prep: casts + Wo dup + mask_pack (+ inline tdense) in one launch
    prep_fused<<<45056, 256, 0, stream>>>(x, Wq, Wk, Wv, Wo, mask,
                                          xb, wqkv, wo, mbits, tdense);

    // fused QKV projection (plain bf16, K=1024) + RoPE + V-transpose
    gemm_mfma<2, 1024><<<dim3(24, 64), 256, 0, stream>>>(xb, wqkv, nullptr,
                                                         qbf, kbf, vt, cost, sint, ts);

    flash_mfma<<<2048, 256, 0, stream>>>(qbf, kbf, vt, mbits, tdense, xs);

    // Wo GEMM in 2-term split precision (K=2048)
    gemm_mfma<0, K2><<<dim3(8, 64), 256, 0, stream>>>(xs, wo, out,
                                                      nullptr, nullptr, nullptr,
                                                      nullptr, nullptr, nullptr);
}

// Round 13
// 299.722 us; speedup vs baseline: 1.3076x; 1.3076x over previous
//
#include <hip/hip_runtime.h>
#include <hip/hip_bf16.h>

#define B_   8
#define T_   1024
#define HID_ 1024
#define NH_  16
#define HD_  64
#define K2   2048   // 2-term split K for the Wo GEMM: [hi|lo] x [hi|hi]

typedef __attribute__((ext_vector_type(8))) short bf16x8;
typedef __attribute__((ext_vector_type(4))) float f32x4;

__device__ __forceinline__ void gl_lds16(const void* g, void* l) {
    __builtin_amdgcn_global_load_lds((const __attribute__((address_space(1))) void*)g,
                                     (__attribute__((address_space(3))) void*)l, 16, 0, 0);
}

__device__ __forceinline__ float fast_exp2(float x) {
    return __builtin_amdgcn_exp2f(x);   // v_exp_f32
}

// ---------------------------------------------------------------------------
// Fused prep v13 (14336 blocks, was 45056 -- CP dispatch + per-thread ILP):
//   [0,4096)      : cast x (8 floats/thread: 2x float4 -> 1x 16B store)
//   [4096,4608)   : cast Wq      [4608,5120)  : cast Wk
//   [5120,5632)   : cast Wv      [5632,6144)  : dup-cast Wo ([hi|hi] K2)
//   [6144,14336)  : mask_pack, 4 ballots/wave (16 mbits words per block)
// tdense is GONE (v13): flash derives density in-wave from mbits.
// ---------------------------------------------------------------------------
__global__ __launch_bounds__(256) void prep_fused(const float* __restrict__ x,
                                                  const float* __restrict__ Wq,
                                                  const float* __restrict__ Wk,
                                                  const float* __restrict__ Wv,
                                                  const float* __restrict__ Wo,
                                                  const int* __restrict__ mask,
                                                  __hip_bfloat16* __restrict__ xb,
                                                  __hip_bfloat16* __restrict__ wqkv,
                                                  __hip_bfloat16* __restrict__ wo,
                                                  unsigned long long* __restrict__ mbits) {
    const int bid = blockIdx.x;
    const int tid = threadIdx.x;
    if (bid < 6144) {
        const float* X;
        __hip_bfloat16* Y;
        int lb;
        if (bid < 4096)      { X = x;  Y = xb;                          lb = bid; }
        else if (bid < 4608) { X = Wq; Y = wqkv;                        lb = bid - 4096; }
        else if (bid < 5120) { X = Wk; Y = wqkv + (size_t)1024 * 1024;  lb = bid - 4608; }
        else if (bid < 5632) { X = Wv; Y = wqkv + (size_t)2048 * 1024;  lb = bid - 5120; }
        else                 { X = Wo; Y = wo;                          lb = bid - 5632; }
        int gid = lb * 256 + tid;
        int f = gid << 3;                      // 8 floats per thread
        float4 a0 = *(const float4*)(X + f);
        float4 a1 = *(const float4*)(X + f + 4);
        union { __hip_bfloat16 b[8]; bf16x8 v; } p;
        p.b[0] = __float2bfloat16(a0.x);
        p.b[1] = __float2bfloat16(a0.y);
        p.b[2] = __float2bfloat16(a0.z);
        p.b[3] = __float2bfloat16(a0.w);
        p.b[4] = __float2bfloat16(a1.x);
        p.b[5] = __float2bfloat16(a1.y);
        p.b[6] = __float2bfloat16(a1.z);
        p.b[7] = __float2bfloat16(a1.w);
        if (bid < 5632) {
            *(bf16x8*)(Y + f) = p.v;
        } else {
            int m = f >> 10, kk = f & 1023;    // kk is a multiple of 8
            size_t base = (size_t)m * K2 + kk;
            *(bf16x8*)(Y + base) = p.v;
            *(bf16x8*)(Y + base + 1024) = p.v;
        }
    } else {
        const int blk = bid - 6144;            // 0..8191
        const int w = tid >> 6, lane = tid & 63;
        const int widbase = blk * 16 + w * 4;  // 16 mbits words per block
#pragma unroll
        for (int j = 0; j < 4; ++j) {
            int wid = widbase + j;             // (b*T + t)*16 + kt
            int m = mask[(size_t)wid * 64 + lane];
            unsigned long long bal = __ballot(m != 0);
            if (lane == 0) mbits[wid] = bal;
        }
    }
}

// ---------------------------------------------------------------------------
// bf16 MFMA GEMM, v7-verified K-loop (best measured config): 128x128 tile,
// BK=64 staged as TWO 128x32 column-blocks; stage -> barrier -> compute both
// -> barrier. 32KB LDS, 4 blocks/CU.
// Dead levers (measured, do not retry): (256,5) [v6: 64V+64A=128 regs caps 4
// waves/SIMD; 5 forces spill]; XCD swizzle [v8: FETCH 79->85MB]; BK=32
// explicit dbuf [v9: 75->84us, halves MLP/ILP; TLP already hides latency];
// BN=64 Wo tile [v10: Wo 60->72us, arithmetic intensity loss beats TLP gain].
// KD = K depth. MODE 0: fp32 C (Wo GEMM). MODE 2: fused QKV epilogue.
// ---------------------------------------------------------------------------
template<int MODE, int KD>
__global__ __launch_bounds__(256, 4) void gemm_mfma(const __hip_bfloat16* __restrict__ A,
                                                    const __hip_bfloat16* __restrict__ Wp,
                                                    float* __restrict__ C0,
                                                    __hip_bfloat16* __restrict__ qbf,
                                                    __hip_bfloat16* __restrict__ kbf,
                                                    __hip_bfloat16* __restrict__ vt,
                                                    const float* __restrict__ cost,
                                                    const float* __restrict__ sint,
                                                    const int* __restrict__ ts) {
    __shared__ __hip_bfloat16 As[2][128 * 32];
    __shared__ __hip_bfloat16 Bs[2][128 * 32];
    const int tid = threadIdx.x;
    const int lane = tid & 63;
    const int w = tid >> 6;
    const int wm = w >> 1, wn = w & 1;
    const int m0 = blockIdx.y * 128, n0 = blockIdx.x * 128;
    const int r0 = tid >> 2;            // 0..63
    const int ks = (tid & 3) << 3;      // 0,8,16,24
    const int ml = lane & 15;
    const int kg = (lane >> 4) << 3;
    const int q4 = (lane >> 4) << 2;

    f32x4 acc[4][4];
#pragma unroll
    for (int i = 0; i < 4; ++i)
#pragma unroll
        for (int j = 0; j < 4; ++j) acc[i][j] = (f32x4){0.f, 0.f, 0.f, 0.f};

    for (int k0 = 0; k0 < KD; k0 += 64) {
#pragma unroll
        for (int c = 0; c < 2; ++c) {
            const int kc = k0 + c * 32 + ks;
            gl_lds16(A  + (size_t)(m0 + r0)      * KD + kc, &As[c][r0 * 32 + ks]);
            gl_lds16(A  + (size_t)(m0 + 64 + r0) * KD + kc, &As[c][(64 + r0) * 32 + ks]);
            gl_lds16(Wp + (size_t)(n0 + r0)      * KD + kc, &Bs[c][r0 * 32 + ks]);
            gl_lds16(Wp + (size_t)(n0 + 64 + r0) * KD + kc, &Bs[c][(64 + r0) * 32 + ks]);
        }
        __syncthreads();

#pragma unroll
        for (int c = 0; c < 2; ++c) {
            bf16x8 a[4], b[4];
#pragma unroll
            for (int mi = 0; mi < 4; ++mi)
                a[mi] = *(const bf16x8*)(&As[c][(wm * 64 + mi * 16 + ml) * 32 + kg]);
#pragma unroll
            for (int ni = 0; ni < 4; ++ni)
                b[ni] = *(const bf16x8*)(&Bs[c][(wn * 64 + ni * 16 + ml) * 32 + kg]);
#pragma unroll
            for (int mi = 0; mi < 4; ++mi)
#pragma unroll
                for (int ni = 0; ni < 4; ++ni)
                    acc[mi][ni] = __builtin_amdgcn_mfma_f32_16x16x32_bf16(a[mi], b[ni], acc[mi][ni], 0, 0, 0);
        }
        __syncthreads();
    }

    if (MODE == 0) {
#pragma unroll
        for (int mi = 0; mi < 4; ++mi)
#pragma unroll
            for (int ni = 0; ni < 4; ++ni) {
                int n = n0 + wn * 64 + ni * 16 + ml;
#pragma unroll
                for (int r = 0; r < 4; ++r) {
                    int m = m0 + wm * 64 + mi * 16 + q4 + r;
                    C0[(size_t)m * 1024 + n] = acc[mi][ni][r];
                }
            }
    } else {
        const int nB = n0 + wn * 64;        // wave-uniform, 64-aligned
        const int sel = nB >> 10;           // 0=Q 1=K 2=V
        const int h = (nB & 1023) >> 6;
        if (sel < 2) {
            __hip_bfloat16* dst = sel ? kbf : qbf;
#pragma unroll
            for (int mi = 0; mi < 4; ++mi) {
#pragma unroll
                for (int r = 0; r < 4; ++r) {
                    int m = m0 + wm * 64 + mi * 16 + q4 + r;
                    int tsv = ts[m];
                    int bb = m >> 10, t = m & 1023;
                    size_t rowoff = ((size_t)(bb * NH_ + h) * T_ + t) * HD_;
#pragma unroll
                    for (int ni = 0; ni < 4; ++ni) {
                        int d = ni * 16 + ml;
                        float c = cost[tsv * HD_ + d];
                        float s = sint[tsv * HD_ + d];
                        float u  = acc[mi][ni][r];
                        float up = acc[mi][ni ^ 2][r];
                        float o = (ni < 2) ? (u * c - up * s) : (u * c + up * s);
                        dst[rowoff + d] = __float2bfloat16(o);
                    }
                }
            }
        } else {
#pragma unroll
            for (int mi = 0; mi < 4; ++mi)
#pragma unroll
                for (int r = 0; r < 4; ++r) {
                    int m = m0 + wm * 64 + mi * 16 + q4 + r;
                    int bb = m >> 10, t = m & 1023;
#pragma unroll
                    for (int ni = 0; ni < 4; ++ni) {
                        int d = ni * 16 + ml;
                        vt[((size_t)(bb * NH_ + h) * HD_ + d) * T_ + t] =
                            __float2bfloat16(acc[mi][ni][r]);
                    }
                }
        }
    }
}

// ---------------------------------------------------------------------------
// MFMA flash attention v13 = verified v11 structure (Vt LDS-staged restored
// after v12's V-direct regression: 4x V-read redundancy flooded L2 and broke
// xs partial-line write assembly -- WRITE 32->100MB, dur 65->162us).
// Swapped QK^T, swizzled gl_lds16 K/V staging, packed Ps round-trip,
// 2048-block grid, LDS 40960B, 4 blocks/CU.
// NEW in v13: density derived IN-WAVE from mbits (__all(mb==~0)) -- tdense
// buffer, its memset node, and prep's atomicAnd are gone. mb is loaded every
// ktile (16 distinct L2-resident words/wave, merged by HW) exactly as the
// masked path already did.
// ---------------------------------------------------------------------------
__global__ __launch_bounds__(256, 4) void flash_mfma(const __hip_bfloat16* __restrict__ qg,
                                                     const __hip_bfloat16* __restrict__ kg_,
                                                     const __hip_bfloat16* __restrict__ vtg,
                                                     const unsigned long long* __restrict__ mbits,
                                                     __hip_bfloat16* __restrict__ xs) {
    __shared__ __hip_bfloat16 Ks[2][64 * 64];   // 16 KB, granule-swizzled
    __shared__ __hip_bfloat16 Vt[2][64 * 64];   // 16 KB, V^T: [d][kv], swizzled
    __shared__ __hip_bfloat16 Ps[4][16 * 64];   // 8 KB, per-wave P: [q][kv], swizzled
    const int id = blockIdx.x;
    const int qt = (id >> 3) & 15;
    const int hb = ((id >> 7) << 3) | (id & 7);
    const int h = hb & 15, b = hb >> 4;
    const int tid = threadIdx.x;
    const int lane = tid & 63;
    const int w = tid >> 6;
    const int ml = lane & 15;
    const int g4 = lane >> 4;                 // 0..3
    const int kg8 = g4 << 3;
    const int q4 = g4 << 2;
    const int q0 = qt * 64;
    const size_t bh_off = (size_t)(b * NH_ + h) * T_ * HD_;
    const __hip_bfloat16* qb = qg + bh_off;
    const __hip_bfloat16* kb = kg_ + bh_off;
    const __hip_bfloat16* vtb = vtg + bh_off;   // (d, t) rows
    const float SCL = 0.125f * 1.44269504f;     // scale * log2(e), for exp2

    // staging geometry: lane covers (row = rbase + lane>>3, dest granule lane&7);
    // source granule pre-swizzled so that LDS slot g' holds global g' ^ (row&7).
    const int srow = lane >> 3;               // 0..7
    const int sg8 = ((lane & 7) ^ srow) << 3; // swizzled source col (bf16 elems)
    // fragment-read swizzle: byte offset of granule g4 at row r is
    //   16 * (g4 ^ (r & 7));  second half (cols +32) is that ^ 64.
    const int sx = ((g4 ^ (ml & 7)) << 4);
    const int pswz = (ml & 7) << 4;           // P-store granule swizzle key

    bf16x8 qf0 = *(const bf16x8*)(qb + (size_t)(q0 + w * 16 + ml) * HD_ + kg8);
    bf16x8 qf1 = *(const bf16x8*)(qb + (size_t)(q0 + w * 16 + ml) * HD_ + 32 + kg8);

    f32x4 acc_o[4];
    float lsum = 0.f;
#pragma unroll
    for (int i = 0; i < 4; ++i) acc_o[i] = (f32x4){0.f, 0.f, 0.f, 0.f};
    char* psw = (char*)&Ps[w][0];

    // prologue: stage ktile 0 into buffer 0 (async; first barrier drains)
#pragma unroll
    for (int p = 0; p < 2; ++p) {
        const int rbase = p * 32 + w * 8;
        gl_lds16(kb  + (size_t)(rbase + srow) * HD_ + sg8, &Ks[0][rbase * 64]);
        gl_lds16(vtb + (size_t)(rbase + srow) * T_  + sg8, &Vt[0][rbase * 64]);
    }

    for (int kt = 0; kt < 16; ++kt) {
        const int cur = kt & 1;
        __syncthreads();   // vmcnt(0): staged tile 'cur' complete; buffer cur^1 free
        if (kt < 15) {
            const int k0n = (kt + 1) * 64;
            const int nb = cur ^ 1;
#pragma unroll
            for (int p = 0; p < 2; ++p) {
                const int rbase = p * 32 + w * 8;
                gl_lds16(kb  + (size_t)(k0n + rbase + srow) * HD_ + sg8, &Ks[nb][rbase * 64]);
                gl_lds16(vtb + (size_t)(rbase + srow) * T_ + k0n + sg8, &Vt[nb][rbase * 64]);
            }
        }

        // S^T = K @ Q^T : sacc[ni][r] = S[q = w*16+ml][kv = ni*16 + q4 + r]
        f32x4 sacc[4];
#pragma unroll
        for (int ni = 0; ni < 4; ++ni) sacc[ni] = (f32x4){0.f, 0.f, 0.f, 0.f};
        const char* ksb = (const char*)&Ks[cur][0];
#pragma unroll
        for (int ni = 0; ni < 4; ++ni) {
            const char* rp = ksb + (ni * 16 + ml) * 128;
            bf16x8 kf0 = *(const bf16x8*)(rp + sx);
            bf16x8 kf1 = *(const bf16x8*)(rp + (sx ^ 64));
            sacc[ni] = __builtin_amdgcn_mfma_f32_16x16x32_bf16(kf0, qf0, sacc[ni], 0, 0, 0);
            sacc[ni] = __builtin_amdgcn_mfma_f32_16x16x32_bf16(kf1, qf1, sacc[ni], 0, 0, 0);
        }

        // softmax numerator (no max subtraction; scores bounded).
        // Density derived in-wave: lane's q-row = w*16+ml; rows repeat 4x
        // across g4 groups, so __all == "all 16 rows fully unmasked".
        unsigned long long mb =
            mbits[((size_t)(b * T_ + q0 + w * 16 + ml)) * 16 + kt];
        if (__all(mb == ~0ull)) {
#pragma unroll
            for (int ni = 0; ni < 4; ++ni) {
                float pv[4];
#pragma unroll
                for (int r = 0; r < 4; ++r) pv[r] = fast_exp2(sacc[ni][r] * SCL);
                lsum += (pv[0] + pv[1]) + (pv[2] + pv[3]);
                union { __hip_bfloat16 bb[4]; unsigned long long u8; } pk;
                pk.bb[0] = __float2bfloat16(pv[0]);
                pk.bb[1] = __float2bfloat16(pv[1]);
                pk.bb[2] = __float2bfloat16(pv[2]);
                pk.bb[3] = __float2bfloat16(pv[3]);
                *(unsigned long long*)(psw + ml * 128 + ((ni * 32 + g4 * 8) ^ pswz)) = pk.u8;
            }
        } else {
#pragma unroll
            for (int ni = 0; ni < 4; ++ni) {
                float pv[4];
#pragma unroll
                for (int r = 0; r < 4; ++r) {
                    int kv = ni * 16 + q4 + r;
                    pv[r] = ((mb >> kv) & 1ull) ? fast_exp2(sacc[ni][r] * SCL) : 0.f;
                }
                lsum += (pv[0] + pv[1]) + (pv[2] + pv[3]);
                union { __hip_bfloat16 bb[4]; unsigned long long u8; } pk;
                pk.bb[0] = __float2bfloat16(pv[0]);
                pk.bb[1] = __float2bfloat16(pv[1]);
                pk.bb[2] = __float2bfloat16(pv[2]);
                pk.bb[3] = __float2bfloat16(pv[3]);
                *(unsigned long long*)(psw + ml * 128 + ((ni * 32 + g4 * 8) ^ pswz)) = pk.u8;
            }
        }

        // P fragments: lane needs P[q=ml][kv = 8g4+e] and [32+8g4+e] -> two
        // 16B-contiguous swizzled reads (same sx un-swizzle as K/V rows).
        bf16x8 pf0 = *(const bf16x8*)(psw + ml * 128 + sx);
        bf16x8 pf1 = *(const bf16x8*)(psw + ml * 128 + (sx ^ 64));

        // O += P @ V
        const char* vsb = (const char*)&Vt[cur][0];
#pragma unroll
        for (int dt = 0; dt < 4; ++dt) {
            const char* rp = vsb + (dt * 16 + ml) * 128;
            bf16x8 vf0 = *(const bf16x8*)(rp + sx);
            bf16x8 vf1 = *(const bf16x8*)(rp + (sx ^ 64));
            acc_o[dt] = __builtin_amdgcn_mfma_f32_16x16x32_bf16(pf0, vf0, acc_o[dt], 0, 0, 0);
            acc_o[dt] = __builtin_amdgcn_mfma_f32_16x16x32_bf16(pf1, vf1, acc_o[dt], 0, 0, 0);
        }
    }

    // epilogue: lane's lsum covers kv in {16ni+q4+r} for q = w*16+ml.
    // Reduce across the 4 lane-groups sharing ml -> total l per q-row.
    float l = lsum;
    l += __shfl_xor(l, 16);
    l += __shfl_xor(l, 32);
    // acc_o rows are q = q4+r: pull l for that row from lane (16*g4 + q4+r).
#pragma unroll
    for (int r = 0; r < 4; ++r) {
        float lr = __shfl(l, q4 + r, 16);
        float inv = 1.0f / lr;
        size_t rb = (size_t)(b * T_ + q0 + w * 16 + q4 + r) * K2;
#pragma unroll
        for (int dt = 0; dt < 4; ++dt) {
            float val = acc_o[dt][r] * inv;
            int col = h * HD_ + dt * 16 + ml;
            __hip_bfloat16 hi = __float2bfloat16(val);
            __hip_bfloat16 lo = __float2bfloat16(val - __bfloat162float(hi));
            xs[rb + col] = hi;
            xs[rb + 1024 + col] = lo;
        }
    }
}

// ---------------------------------------------------------------------------
extern "C" void kernel_launch(void* const* d_in, const int* in_sizes, int n_in,
                              void* d_out, int out_size, void* d_ws, size_t ws_size,
                              hipStream_t stream) {
    const float* x    = (const float*)d_in[0];
    const float* Wq   = (const float*)d_in[1];
    const float* Wk   = (const float*)d_in[2];
    const float* Wv   = (const float*)d_in[3];
    const float* Wo   = (const float*)d_in[4];
    const float* cost = (const float*)d_in[5];
    const float* sint = (const float*)d_in[6];
    const int*   mask = (const int*)d_in[7];
    const int*   ts   = (const int*)d_in[8];
    float* out = (float*)d_out;

    const size_t MB = 1ull << 20;
    char* wsp = (char*)d_ws;
    __hip_bfloat16* qbf  = (__hip_bfloat16*)(wsp + 0 * MB);     // 16 MB
    __hip_bfloat16* kbf  = (__hip_bfloat16*)(wsp + 16 * MB);    // 16 MB
    __hip_bfloat16* vt   = (__hip_bfloat16*)(wsp + 32 * MB);    // 16 MB (b,h,d,t)
    __hip_bfloat16* xs   = (__hip_bfloat16*)(wsp + 48 * MB);    // 32 MB (ctx 2-term split)
    __hip_bfloat16* xb   = (__hip_bfloat16*)(wsp + 80 * MB);    // 16 MB (x cast)
    __hip_bfloat16* wqkv = (__hip_bfloat16*)(wsp + 96 * MB);    // 6 MB (3072 x 1024)
    __hip_bfloat16* wo   = (__hip_bfloat16*)(wsp + 102 * MB);   // 4 MB (1024 x K2)
    unsigned long long* mbits = (unsigned long long*)(wsp + 106 * MB);  // 1 MB

    // fused prep: casts + Wo dup + mask_pack in one launch (no tdense/memset)
    prep_fused<<<14336, 256, 0, stream>>>(x, Wq, Wk, Wv, Wo, mask,
                                          xb, wqkv, wo, mbits);

    // fused QKV projection (plain bf16, K=1024) + RoPE + V-transpose
    gemm_mfma<2, 1024><<<dim3(24, 64), 256, 0, stream>>>(xb, wqkv, nullptr,
                                                         qbf, kbf, vt, cost, sint, ts);

    flash_mfma<<<2048, 256, 0, stream>>>(qbf, kbf, vt, mbits, xs);

    // Wo GEMM in 2-term split precision (K=2048)
    gemm_mfma<0, K2><<<dim3(8, 64), 256, 0, stream>>>(xs, wo, out,
                                                      nullptr, nullptr, nullptr,
                                                      nullptr, nullptr, nullptr);
}